// Round 2
// 1633.896 us; speedup vs baseline: 1.1228x; 1.1228x over previous
//
#include <hip/hip_runtime.h>

// B=4, T=2048, C=1024, H=16, D=64
// outputs: y [4,2048,1024] fp32, att [4,16,2048,2048] fp32 (concat in d_out)

using bf16x8 = __attribute__((ext_vector_type(8))) short;
using f32x4  = __attribute__((ext_vector_type(4))) float;

__device__ __forceinline__ unsigned short f2bf(float f) {
    union { float f; unsigned u; } v; v.f = f;
    unsigned u = v.u;
    return (unsigned short)((u + 0x7fffu + ((u >> 16) & 1u)) >> 16);
}

// ---------------- convert x (fp32 -> bf16) ----------------
__global__ __launch_bounds__(256) void convert_x(const float* __restrict__ x,
                                                 short* __restrict__ xb, int n4) {
    int i = blockIdx.x * 256 + threadIdx.x;
    if (i < n4) {
        float4 v = ((const float4*)x)[i];
        ushort4 o;
        o.x = f2bf(v.x); o.y = f2bf(v.y); o.z = f2bf(v.z); o.w = f2bf(v.w);
        ((ushort4*)xb)[i] = o;
    }
}

// ---------------- transpose weights: W[in][out] fp32 -> Wt[out][in] bf16 ----------------
// z: 0=Wq 1=Wk 2=Wv 3=Wp, Wt rows offset z*1024
__global__ __launch_bounds__(256) void transpose_w(const float* __restrict__ Wq,
                                                   const float* __restrict__ Wk,
                                                   const float* __restrict__ Wv,
                                                   const float* __restrict__ Wp,
                                                   short* __restrict__ Wt) {
    __shared__ float tile[32][33];
    int z = blockIdx.z;
    const float* src = (z == 0) ? Wq : (z == 1) ? Wk : (z == 2) ? Wv : Wp;
    short* dst = Wt + (size_t)z * 1024 * 1024;
    int n0 = blockIdx.x * 32, k0 = blockIdx.y * 32;
    int tx = threadIdx.x, ty = threadIdx.y;
#pragma unroll
    for (int r = 0; r < 32; r += 8)
        tile[ty + r][tx] = src[(size_t)(k0 + ty + r) * 1024 + n0 + tx];
    __syncthreads();
#pragma unroll
    for (int r = 0; r < 32; r += 8)
        dst[(size_t)(n0 + ty + r) * 1024 + k0 + tx] = (short)f2bf(tile[tx][ty + r]);
}

// ---------------- GEMM: C[m][n] = A[m][:] . Bt[n][:], K=1024, tiles 128x128, BK=32 ----------------
// MODE 0: QKV epilogue -> Qh[b,h,t,d] (prescaled 1/8), Kh[b,h,t,d], Vt[b,h,d,t]  (bf16)
// MODE 1: proj epilogue -> Yout[m][n] fp32 + bias
template <int MODE>
__global__ __launch_bounds__(256) void gemm_bt(
    const short* __restrict__ A, const short* __restrict__ Bt,
    const float* __restrict__ bias0, const float* __restrict__ bias1,
    const float* __restrict__ bias2,
    short* __restrict__ Qh, short* __restrict__ Kh, short* __restrict__ Vth,
    float* __restrict__ Yout) {
    constexpr int K = 1024;
    __shared__ short As[128 * 40];  // padded stride 40 (80B, 16B-aligned rows)
    __shared__ short Bs[128 * 40];
    int tid = threadIdx.x;
    int m0 = blockIdx.y * 128;
    int n0 = blockIdx.x * 128;
    int srow = tid >> 2;
    int scol = (tid & 3) << 3;
    int lane = tid & 63;
    int wave = tid >> 6;
    int wm = (wave >> 1) << 6;
    int wn = (wave & 1) << 6;
    int lr = lane & 15;
    int lq = lane >> 4;
    f32x4 acc[4][4];
#pragma unroll
    for (int i = 0; i < 4; i++)
#pragma unroll
        for (int j = 0; j < 4; j++) acc[i][j] = (f32x4){0.f, 0.f, 0.f, 0.f};

    for (int k0 = 0; k0 < K; k0 += 32) {
        __syncthreads();
#pragma unroll
        for (int p = 0; p < 2; ++p) {
            int row = p * 64 + srow;
            *(uint4*)&As[row * 40 + scol] =
                *(const uint4*)&A[(size_t)(m0 + row) * K + k0 + scol];
            *(uint4*)&Bs[row * 40 + scol] =
                *(const uint4*)&Bt[(size_t)(n0 + row) * K + k0 + scol];
        }
        __syncthreads();
        bf16x8 af[4], bfr[4];
#pragma unroll
        for (int i = 0; i < 4; i++)
            af[i] = *(const bf16x8*)&As[(wm + i * 16 + lr) * 40 + lq * 8];
#pragma unroll
        for (int j = 0; j < 4; j++)
            bfr[j] = *(const bf16x8*)&Bs[(wn + j * 16 + lr) * 40 + lq * 8];
#pragma unroll
        for (int i = 0; i < 4; i++)
#pragma unroll
            for (int j = 0; j < 4; j++)
                acc[i][j] = __builtin_amdgcn_mfma_f32_16x16x32_bf16(af[i], bfr[j],
                                                                    acc[i][j], 0, 0, 0);
    }

    // epilogue: C/D layout col=lane&15, row=quad*4+reg
#pragma unroll
    for (int i = 0; i < 4; i++) {
        int m_base = m0 + wm + i * 16 + lq * 4;
#pragma unroll
        for (int j = 0; j < 4; j++) {
            int n_g = n0 + wn + j * 16 + lr;
            if (MODE == 0) {
                int which = n_g >> 10;
                int nn = n_g & 1023;
                int h = nn >> 6, d = nn & 63;
                const float* bs = (which == 0) ? bias0 : (which == 1) ? bias1 : bias2;
                float bv_ = bs[nn];
#pragma unroll
                for (int r = 0; r < 4; r++) {
                    int m_g = m_base + r;
                    int b = m_g >> 11, t = m_g & 2047;
                    float v = acc[i][j][r] + bv_;
                    size_t head = (size_t)(b * 16 + h);
                    if (which == 0)
                        Qh[(head * 2048 + t) * 64 + d] = (short)f2bf(v * 0.125f);
                    else if (which == 1)
                        Kh[(head * 2048 + t) * 64 + d] = (short)f2bf(v);
                    else
                        Vth[(head * 64 + d) * 2048 + t] = (short)f2bf(v);
                }
            } else {
                float bv_ = bias0[n_g];
#pragma unroll
                for (int r = 0; r < 4; r++) {
                    int m_g = m_base + r;
                    Yout[(size_t)m_g * 1024 + n_g] = acc[i][j][r] + bv_;
                }
            }
        }
    }
}

// ---------------- attention: one wave per PAIR of 16-query tiles (balanced) ----------------
// Q prescaled by 1/sqrt(D). Wave wv handles qt = wv and qt = 127 - wv (work = 129 tiles, uniform).
// Phase 1: softmax denominators (no max: logits bounded).
// Phase 2: recompute S, stage probs in LDS (bf16 for PV A-frag, f32 for vectorized att store).
// No workgroup fences: P staging is same-wave-only LDS (in-order DS pipe), double-buffered on c&1.
__global__ __launch_bounds__(256) void attn_kernel(
    const short* __restrict__ Qh, const short* __restrict__ Kh,
    const short* __restrict__ Vt, float* __restrict__ att, short* __restrict__ Yb) {
    __shared__ __attribute__((aligned(16))) short Pl[2][4][16 * 40];  // bf16 P (A-layout src)
    __shared__ __attribute__((aligned(16))) float Pf[2][4][16 * 36];  // f32 probs for att stores
    int tid = threadIdx.x;
    int lane = tid & 63;
    int wave = tid >> 6;
    int wv = blockIdx.x * 4 + wave;  // 0..63
    int bh = blockIdx.y;             // 0..63
    int b = bh >> 4, h = bh & 15;
    const short* Qp = Qh + (size_t)bh * (2048 * 64);
    const short* Kp = Kh + (size_t)bh * (2048 * 64);
    const short* Vp = Vt + (size_t)bh * (2048 * 64);
    float* attp = att + (size_t)bh * 2048 * 2048;
    int lr = lane & 15, lq = lane >> 4;

#pragma unroll 1
    for (int pass = 0; pass < 2; ++pass) {
        int qt = pass ? (127 - wv) : wv;  // balanced pair
        int q0 = qt << 4;

        // A-layout Q fragments: lane holds Q[q0+lr][lq*8 + j(+32)]
        bf16x8 qa0 = *(const bf16x8*)&Qp[(q0 + lr) * 64 + lq * 8];
        bf16x8 qa1 = *(const bf16x8*)&Qp[(q0 + lr) * 64 + 32 + lq * 8];

        // ---- phase 1: row sums of exp(logit) ----
        f32x4 lsum = {0.f, 0.f, 0.f, 0.f};
        for (int kt = 0; kt < qt; ++kt) {  // strictly-below-diagonal tiles: no mask needed
            const short* kr = &Kp[(kt * 16 + lr) * 64 + lq * 8];
            bf16x8 kb0 = *(const bf16x8*)kr;
            bf16x8 kb1 = *(const bf16x8*)(kr + 32);
            f32x4 s = __builtin_amdgcn_mfma_f32_16x16x32_bf16(
                qa0, kb0, (f32x4){0.f, 0.f, 0.f, 0.f}, 0, 0, 0);
            s = __builtin_amdgcn_mfma_f32_16x16x32_bf16(qa1, kb1, s, 0, 0, 0);
#pragma unroll
            for (int r = 0; r < 4; r++) lsum[r] += __expf(s[r]);
        }
        {  // diagonal tile: causal mask
            const short* kr = &Kp[(qt * 16 + lr) * 64 + lq * 8];
            bf16x8 kb0 = *(const bf16x8*)kr;
            bf16x8 kb1 = *(const bf16x8*)(kr + 32);
            f32x4 s = __builtin_amdgcn_mfma_f32_16x16x32_bf16(
                qa0, kb0, (f32x4){0.f, 0.f, 0.f, 0.f}, 0, 0, 0);
            s = __builtin_amdgcn_mfma_f32_16x16x32_bf16(qa1, kb1, s, 0, 0, 0);
#pragma unroll
            for (int r = 0; r < 4; r++)
                lsum[r] += (lr <= lq * 4 + r) ? __expf(s[r]) : 0.0f;
        }
#pragma unroll
        for (int m = 1; m < 16; m <<= 1) {
#pragma unroll
            for (int r = 0; r < 4; r++) lsum[r] += __shfl_xor(lsum[r], m, 64);
        }
        float rl[4];
#pragma unroll
        for (int r = 0; r < 4; r++) rl[r] = 1.0f / lsum[r];

        // ---- phase 2: recompute, stage probs, vectorized att write, PV ----
        f32x4 o[4];
#pragma unroll
        for (int j = 0; j < 4; j++) o[j] = (f32x4){0.f, 0.f, 0.f, 0.f};
        int nchunk = (qt >> 1) + 1;  // 32-key chunks
        for (int c = 0; c < nchunk; ++c) {
            short* Pw = Pl[c & 1][wave];
            float* Pfw = Pf[c & 1][wave];
#pragma unroll
            for (int half = 0; half < 2; ++half) {
                int kt = c * 2 + half;
                if (kt <= qt) {
                    const short* kr = &Kp[(kt * 16 + lr) * 64 + lq * 8];
                    bf16x8 kb0 = *(const bf16x8*)kr;
                    bf16x8 kb1 = *(const bf16x8*)(kr + 32);
                    f32x4 s = __builtin_amdgcn_mfma_f32_16x16x32_bf16(
                        qa0, kb0, (f32x4){0.f, 0.f, 0.f, 0.f}, 0, 0, 0);
                    s = __builtin_amdgcn_mfma_f32_16x16x32_bf16(qa1, kb1, s, 0, 0, 0);
                    int colg = kt * 16 + lr;
#pragma unroll
                    for (int r = 0; r < 4; r++) {
                        int rowg = q0 + lq * 4 + r;
                        float p = (colg <= rowg) ? __expf(s[r]) * rl[r] : 0.0f;
                        Pw[(lq * 4 + r) * 40 + half * 16 + lr] = (short)f2bf(p);
                        Pfw[(lq * 4 + r) * 36 + half * 16 + lr] = p;
                    }
                } else {
#pragma unroll
                    for (int r = 0; r < 4; r++) {
                        Pw[(lq * 4 + r) * 40 + half * 16 + lr] = 0;
                        Pfw[(lq * 4 + r) * 36 + half * 16 + lr] = 0.0f;
                    }
                }
            }
            // LDS-only drain: same-wave write->read (DS pipe is in-order per wave)
            asm volatile("s_waitcnt lgkmcnt(0)" ::: "memory");

            // vectorized att store: 16 rows x 32 cols fp32, 2 float4 per lane
#pragma unroll
            for (int it = 0; it < 2; ++it) {
                int row = (it * 64 + lane) >> 3;
                int c4 = (lane & 7) << 2;
                float4 pv = *(const float4*)&Pfw[row * 36 + c4];
                *(float4*)&attp[(size_t)(q0 + row) * 2048 + c * 32 + c4] = pv;
            }

            bf16x8 pfr = *(const bf16x8*)&Pw[lr * 40 + lq * 8];  // A-layout P
#pragma unroll
            for (int j = 0; j < 4; j++) {
                bf16x8 vf = *(const bf16x8*)&Vp[(j * 16 + lr) * 2048 + c * 32 + lq * 8];
                o[j] = __builtin_amdgcn_mfma_f32_16x16x32_bf16(pfr, vf, o[j], 0, 0, 0);
            }
        }

        // zero-fill the masked-out upper region (cols >= nchunk*32; chunk store covered the rest)
        int zc0 = nchunk * 32;
        for (int r = 0; r < 16; ++r) {
            float* rowp = attp + (size_t)(q0 + r) * 2048;
            for (int c = zc0 + lane * 4; c < 2048; c += 256)
                *(float4*)(rowp + c) = (float4){0.f, 0.f, 0.f, 0.f};
        }

        // write O (C-layout) to Yb[b,t,h*64+d] bf16
#pragma unroll
        for (int j = 0; j < 4; j++)
#pragma unroll
            for (int r = 0; r < 4; r++)
                Yb[(size_t)(b * 2048 + q0 + lq * 4 + r) * 1024 + h * 64 + j * 16 + lr] =
                    (short)f2bf(o[j][r]);
    }
}

extern "C" void kernel_launch(void* const* d_in, const int* in_sizes, int n_in,
                              void* d_out, int out_size, void* d_ws, size_t ws_size,
                              hipStream_t stream) {
    const float* x  = (const float*)d_in[0];
    const float* Wq = (const float*)d_in[1];
    const float* bq = (const float*)d_in[2];
    const float* Wk = (const float*)d_in[3];
    const float* bk = (const float*)d_in[4];
    const float* Wv = (const float*)d_in[5];
    const float* bv = (const float*)d_in[6];
    const float* Wp = (const float*)d_in[7];
    const float* bp = (const float*)d_in[8];

    float* y = (float*)d_out;
    float* att = y + (size_t)4 * 2048 * 1024;  // second output

    // workspace layout (bf16 buffers), total 88 MiB
    char* ws = (char*)d_ws;
    short* xb = (short*)(ws);                   // [8192][1024]
    short* Wt = (short*)(ws + 16777216);        // [4096][1024] (q,k,v,p transposed)
    short* Qh = (short*)(ws + 25165824);        // [B,H,T,D]
    short* Kh = (short*)(ws + 41943040);        // [B,H,T,D]
    short* Vt = (short*)(ws + 58720256);        // [B,H,D,T]
    short* Yb = (short*)(ws + 75497472);        // [8192][1024]

    convert_x<<<8192, 256, 0, stream>>>(x, xb, 2097152);
    transpose_w<<<dim3(32, 32, 4), dim3(32, 8), 0, stream>>>(Wq, Wk, Wv, Wp, Wt);
    gemm_bt<0><<<dim3(24, 64), 256, 0, stream>>>(xb, Wt, bq, bk, bv, Qh, Kh, Vt,
                                                 (float*)nullptr);
    attn_kernel<<<dim3(16, 64), 256, 0, stream>>>(Qh, Kh, Vt, att, Yb);
    gemm_bt<1><<<dim3(8, 64), 256, 0, stream>>>(Yb, Wt + (size_t)3072 * 1024, bp,
                                                (const float*)nullptr,
                                                (const float*)nullptr,
                                                (short*)nullptr, (short*)nullptr,
                                                (short*)nullptr, y);
}